// Round 15
// baseline (149.283 us; speedup 1.0000x reference)
//
#include <hip/hip_runtime.h>
#include <hip/hip_bf16.h>

#define N_NODES 50000
#define N_EDGES 800000
#define N_FEAT 512
#define HIDDEN 128
#define N_CLASSES 32

#define NBUCK 196        // coarse buckets: src>>8 (256-node regions)
#define REG_STRIDE 6144  // slots per region (mean 4081, sigma 64 -> 30+ sigma headroom)
#define NCHUNK 7         // dst-chunks: dst>>13 -> 0..6 (8192-node / 2MB L2 windows)

typedef __attribute__((ext_vector_type(8))) short bf16x8;
typedef __attribute__((ext_vector_type(4))) float f32x4;

// round-to-nearest-even f32 -> bf16 bits (cold paths)
static __device__ __forceinline__ unsigned short f2bf(float f) {
    unsigned u = __float_as_uint(f);
    u += 0x7FFFu + ((u >> 16) & 1u);
    return (unsigned short)(u >> 16);
}
// unpack uint = (bf16_hi<<16)|bf16_lo
static __device__ __forceinline__ float bflo(unsigned u) { return __uint_as_float(u << 16); }
static __device__ __forceinline__ float bfhi(unsigned u) { return __uint_as_float(u & 0xFFFF0000u); }
// HW packed cvt: one v_cvt_pk_bf16_f32 (RNE)
static __device__ __forceinline__ unsigned pack2(float a, float b) {
    union { __hip_bfloat162 h; unsigned u; } c;
    c.h = __float22bfloat162_rn(make_float2(a, b));
    return c.u;
}

// ---------------- CSR build, phase 1: LDS-bucketed coarse scatter ----------------
// record: src(16) | dst(16)<<16 | val_bits<<32

__global__ __launch_bounds__(256) void bucket1_k(const int* __restrict__ src, const int* __restrict__ dst,
                                                 const float* __restrict__ val,
                                                 int* __restrict__ gcursor,
                                                 unsigned long long* __restrict__ tmp) {
    __shared__ int cnt[256];
    __shared__ int lstart[256];
    __shared__ int lcur[256];
    __shared__ int gbase[256];
    __shared__ unsigned long long buf[2048];   // 16 KB
    const int t = threadIdx.x;
    const int e0 = blockIdx.x * 2048;
    const int ne = min(2048, N_EDGES - e0);

    cnt[t] = 0;
    __syncthreads();

    unsigned long long rec[8];
    int rb[8];
#pragma unroll
    for (int j = 0; j < 8; ++j) {
        int p = j * 256 + t;
        rec[j] = 0; rb[j] = -1;
        if (p < ne) {
            int i = e0 + p;
            unsigned s = (unsigned)src[i];
            rec[j] = (unsigned long long)(s | ((unsigned)dst[i] << 16))
                   | ((unsigned long long)__float_as_uint(val[i]) << 32);
            int b = (int)(s >> 8);
            rb[j] = b;
            atomicAdd(&cnt[b], 1);
        }
    }
    __syncthreads();
    const int cv = cnt[t];
    // inclusive scan (Hillis-Steele)
    for (int off = 1; off < 256; off <<= 1) {
        int xv = (t >= off) ? cnt[t - off] : 0;
        __syncthreads();
        cnt[t] += xv;
        __syncthreads();
    }
    lstart[t] = cnt[t] - cv;
    lcur[t]   = cnt[t] - cv;
    if (t < NBUCK) gbase[t] = atomicAdd(&gcursor[t], cv);
    __syncthreads();
    // place records bucket-grouped into LDS
#pragma unroll
    for (int j = 0; j < 8; ++j) {
        if (rb[j] >= 0) {
            int pos = atomicAdd(&lcur[rb[j]], 1);
            buf[pos] = rec[j];
        }
    }
    __syncthreads();
    // burst write-out: consecutive p within a bucket -> consecutive global slots
#pragma unroll
    for (int j = 0; j < 8; ++j) {
        int p = j * 256 + t;
        if (p < ne) {
            unsigned long long r = buf[p];
            int b = (int)((r & 0xFFFFu) >> 8);
            int tgt = gbase[b] + (p - lstart[b]);
            tmp[(size_t)b * REG_STRIDE + tgt] = r;
        }
    }
}

// ---------------- CSR build, phase 2: per-region sort by (node, dst-chunk) + row_ptr ----------------

__global__ __launch_bounds__(256) void bucket2_k(const int* __restrict__ gcursor,
                                                 const unsigned long long* __restrict__ tmp,
                                                 unsigned long long* __restrict__ csr_ev,
                                                 int* __restrict__ row_ptr) {
    __shared__ int lcnt[256 * NCHUNK];   // [node][chunk]
    __shared__ int lcur[256 * NCHUNK];
    __shared__ int rowsum[256];
    __shared__ int cnts[NBUCK];
    __shared__ int base_s;
    const int b = blockIdx.x;
    const int t = threadIdx.x;
    if (t < NBUCK) cnts[t] = gcursor[t];
    for (int j = t; j < 256 * NCHUNK; j += 256) lcnt[j] = 0;
    __syncthreads();
    const int nb = cnts[b];
    if (t == 0) {
        int s = 0;
        for (int r = 0; r < b; ++r) s += cnts[r];
        base_s = s;
    }
    const unsigned long long* reg = tmp + (size_t)b * REG_STRIDE;
    __syncthreads();
    // pass 1: per-(node,chunk) counts (local node = rec & 255; chunk = dst>>13)
    for (int p = t; p < nb; p += 256) {
        unsigned long long r = reg[p];
        int n = (int)(r & 0xFFu);
        int ch = (int)(((r >> 16) & 0xFFFFu) >> 13);
        atomicAdd(&lcnt[n * NCHUNK + ch], 1);
    }
    __syncthreads();
    // two-level scan: per-thread 7-seq sum, Hillis-Steele over row sums
    int rs = 0;
#pragma unroll
    for (int c = 0; c < NCHUNK; ++c) rs += lcnt[t * NCHUNK + c];
    rowsum[t] = rs;
    __syncthreads();
    for (int off = 1; off < 256; off <<= 1) {
        int xv = (t >= off) ? rowsum[t - off] : 0;
        __syncthreads();
        rowsum[t] += xv;
        __syncthreads();
    }
    const int start = base_s + rowsum[t] - rs;   // exclusive row start
    int o = start;
#pragma unroll
    for (int c = 0; c < NCHUNK; ++c) { lcur[t * NCHUNK + c] = o; o += lcnt[t * NCHUNK + c]; }
    int node = b * 256 + t;
    if (node <= N_NODES) row_ptr[node] = start;
    __syncthreads();
    // pass 2: place in (node, chunk) order (L2-hot window)
    for (int p = t; p < nb; p += 256) {
        unsigned long long r = reg[p];
        int n = (int)(r & 0xFFu);
        int ch = (int)(((r >> 16) & 0xFFFFu) >> 13);
        int pos = atomicAdd(&lcur[n * NCHUNK + ch], 1);
        csr_ev[pos] = ((r >> 16) & 0xFFFFull) | (r & 0xFFFFFFFF00000000ull);
    }
}

// ---------------- W1 transpose + bf16 (+ gcursor zero): W1[512][128] -> W1t[128][512] ----------------

__global__ __launch_bounds__(256) void w1conv_k(const float* __restrict__ W1,
                                                unsigned short* __restrict__ W1t,
                                                int* __restrict__ gcursor) {
    if (blockIdx.x == 0 && threadIdx.x < NBUCK) gcursor[threadIdx.x] = 0;
    int id = blockIdx.x * 256 + threadIdx.x;   // 65536
    int c = id >> 9;          // 0..127
    int k = id & 511;         // 0..511
    W1t[(size_t)c * N_FEAT + k] = f2bf(W1[(size_t)k * HIDDEN + c]);
}

// ---------------- GEMM1: whole W1t in LDS; balanced per-wave streaming, depth-3 prefetch ----------------

__global__ __launch_bounds__(1024, 1) void gemm1_mfma(const float* __restrict__ x,
                                                      const unsigned short* __restrict__ W1t,
                                                      unsigned short* __restrict__ pre1b) {
    __shared__ char lds[131072];   // whole W1t, fragment-chunk order

    const int t = threadIdx.x;
    const int w = t >> 6;            // wave 0..15
    const int l = t & 63;
    const int l15 = l & 15;
    const int lhi = l >> 4;

    // stage: wave w loads chunks w*8 .. w*8+7
#pragma unroll
    for (int j = 0; j < 8; ++j) {
        int c = w * 8 + j;           // wave-uniform chunk id
        int n = c & 7, ks = c >> 3;
        int col = n * 16 + l15;
        int k = ks * 32 + lhi * 8;
        __builtin_amdgcn_global_load_lds(W1t + (size_t)col * N_FEAT + k,
                                         (unsigned short*)(lds + c * 1024), 16, 0, 0);
    }
    __syncthreads();   // the only barrier

    const int g = w * 256 + blockIdx.x;    // strided 16-row-group id (balanced per block)
    if (g >= N_NODES / 16) return;

    const float* xr = x + (size_t)(g * 16 + l15) * N_FEAT + lhi * 8;

    f32x4 acc[8];
#pragma unroll
    for (int n = 0; n < 8; ++n) acc[n] = (f32x4){0.f, 0.f, 0.f, 0.f};

    // depth-3 rolling prefetch pipeline (static indices after full unroll)
    float4 qa[3], qb[3];
#pragma unroll
    for (int j = 0; j < 3; ++j) {
        qa[j] = *(const float4*)(xr + j * 32);
        qb[j] = *(const float4*)(xr + j * 32 + 4);
    }
#pragma unroll
    for (int ks = 0; ks < 16; ++ks) {
        float4 c0 = qa[ks % 3], c1 = qb[ks % 3];
        if (ks + 3 < 16) {
            qa[ks % 3] = *(const float4*)(xr + (ks + 3) * 32);
            qb[ks % 3] = *(const float4*)(xr + (ks + 3) * 32 + 4);
        }
        union { bf16x8 v; __hip_bfloat162 h[4]; } u;
        u.h[0] = __float22bfloat162_rn(make_float2(c0.x, c0.y));
        u.h[1] = __float22bfloat162_rn(make_float2(c0.z, c0.w));
        u.h[2] = __float22bfloat162_rn(make_float2(c1.x, c1.y));
        u.h[3] = __float22bfloat162_rn(make_float2(c1.z, c1.w));
        const char* bp = lds + (ks * 8) * 1024 + l * 16;
        __builtin_amdgcn_s_setprio(1);
#pragma unroll
        for (int n = 0; n < 8; ++n) {
            bf16x8 bf = *(const bf16x8*)(bp + n * 1024);
            acc[n] = __builtin_amdgcn_mfma_f32_16x16x32_bf16(u.v, bf, acc[n], 0, 0, 0);
        }
        __builtin_amdgcn_s_setprio(0);
    }
    // epilogue: C/D layout col=lane&15, row=(lane>>4)*4+reg
    unsigned short* orow = pre1b + (size_t)(g * 16 + lhi * 4) * HIDDEN + l15;
#pragma unroll
    for (int n = 0; n < 8; ++n)
#pragma unroll
        for (int j = 0; j < 4; ++j)
            orow[(size_t)j * HIDDEN + n * 16] = f2bf(acc[n][j]);
}

// ---------------- SpMM1 + fused GEMM2: pre2b = bf16( relu(A @ pre1) @ W2 ) ----------------
// One wave per node. Edge loop (4-edge unroll) accumulates the h-row in registers
// (lane l holds h[2l], h[2l+1]). Then fused 128x32 gemv: W2 staged in LDS (16 KB, f32);
// lane l computes col c=l&31 over k-half (l>>5) via 32 shfl-broadcasts + 64 FMA;
// shfl_xor(32) combine; pack bf16; write pre2b. hb buffer eliminated.

__global__ __launch_bounds__(256) void spmm1g2_k(const int* __restrict__ rp,
                                                 const unsigned long long* __restrict__ ce,
                                                 const unsigned* __restrict__ P,
                                                 const float* __restrict__ W2,
                                                 unsigned* __restrict__ pre2b) {
    __shared__ float w2s[HIDDEN * N_CLASSES];   // 16 KB, row-major [k][c]
    const int t = threadIdx.x;
#pragma unroll
    for (int j = 0; j < 4; ++j) {               // 1024 float4
        int f = j * 256 + t;
        *(float4*)&w2s[f * 4] = *(const float4*)(W2 + f * 4);
    }
    __syncthreads();                            // the only barrier

    const int g = t >> 6;
    const int lane = t & 63;
    const int node = blockIdx.x * 4 + g;        // grid 12500*4 = 50000 exactly
    const int s = rp[node], e = rp[node + 1];
    float2 a0, a1, a2, a3;
    a0.x = a0.y = a1.x = a1.y = 0.f;
    a2.x = a2.y = a3.x = a3.y = 0.f;
    int i = s;
    for (; i + 4 <= e; i += 4) {
        unsigned long long e0 = ce[i],     e1 = ce[i + 1];
        unsigned long long e2 = ce[i + 2], e3 = ce[i + 3];
        unsigned u0 = P[(size_t)(unsigned)e0 * 64 + lane];
        unsigned u1 = P[(size_t)(unsigned)e1 * 64 + lane];
        unsigned u2 = P[(size_t)(unsigned)e2 * 64 + lane];
        unsigned u3 = P[(size_t)(unsigned)e3 * 64 + lane];
        float v0 = __uint_as_float((unsigned)(e0 >> 32));
        float v1 = __uint_as_float((unsigned)(e1 >> 32));
        float v2 = __uint_as_float((unsigned)(e2 >> 32));
        float v3 = __uint_as_float((unsigned)(e3 >> 32));
        a0.x += v0 * bflo(u0); a0.y += v0 * bfhi(u0);
        a1.x += v1 * bflo(u1); a1.y += v1 * bfhi(u1);
        a2.x += v2 * bflo(u2); a2.y += v2 * bfhi(u2);
        a3.x += v3 * bflo(u3); a3.y += v3 * bfhi(u3);
    }
    for (; i < e; ++i) {
        unsigned long long e0 = ce[i];
        unsigned u0 = P[(size_t)(unsigned)e0 * 64 + lane];
        float v0 = __uint_as_float((unsigned)(e0 >> 32));
        a0.x += v0 * bflo(u0); a0.y += v0 * bfhi(u0);
    }
    a0.x += a1.x + a2.x + a3.x;
    a0.y += a1.y + a2.y + a3.y;
    a0.x = a0.x > 0.f ? a0.x : 0.f;             // h[2*lane], h[2*lane+1]
    a0.y = a0.y > 0.f ? a0.y : 0.f;

    // fused gemv: lane computes pre2[c], c = lane&31, over k-half (lane>>5)
    const int c = lane & 31;
    const int base = (lane >> 5) * 32;          // source lanes for this k-half
    float acc2 = 0.f;
#pragma unroll
    for (int kk = 0; kk < 32; ++kk) {
        int src = base + kk;
        float hx = __shfl(a0.x, src);           // h[2*src]
        float hy = __shfl(a0.y, src);           // h[2*src+1]
        acc2 += hx * w2s[(2 * src) * N_CLASSES + c] + hy * w2s[(2 * src + 1) * N_CLASSES + c];
    }
    acc2 += __shfl_xor(acc2, 32);               // combine k-halves (lanes 0..31 hold pre2[c])
    const int f2 = lane & 15;
    float v0 = __shfl(acc2, 2 * f2);
    float v1 = __shfl(acc2, 2 * f2 + 1);
    if (lane < 16) pre2b[(size_t)node * 16 + f2] = pack2(v0, v1);
}

// ---------------- SpMM2: out = A @ pre2 ; 16 lanes/edge, 2-deep unroll (8 edges in flight) ----------------

__global__ __launch_bounds__(256) void spmm2_k(const int* __restrict__ rp,
                                               const unsigned long long* __restrict__ ce,
                                               const unsigned* __restrict__ P2,
                                               float* __restrict__ out) {
    const int g = threadIdx.x >> 6;
    const int lane = threadIdx.x & 63;
    const int node = blockIdx.x * 4 + g;
    if (node >= N_NODES) return;
    const int s = rp[node], e = rp[node + 1];
    const int f2 = lane & 15;      // uint index: feats 2*f2, 2*f2+1
    const int par = lane >> 4;     // 0..3
    float ax0 = 0.f, ay0 = 0.f, ax1 = 0.f, ay1 = 0.f;
    int i = s + par;
    for (; i + 4 < e; i += 8) {
        unsigned long long e0 = ce[i], e1 = ce[i + 4];
        unsigned u0 = P2[(size_t)(unsigned)e0 * 16 + f2];
        unsigned u1 = P2[(size_t)(unsigned)e1 * 16 + f2];
        float v0 = __uint_as_float((unsigned)(e0 >> 32));
        float v1 = __uint_as_float((unsigned)(e1 >> 32));
        ax0 += v0 * bflo(u0); ay0 += v0 * bfhi(u0);
        ax1 += v1 * bflo(u1); ay1 += v1 * bfhi(u1);
    }
    if (i < e) {
        unsigned long long e0 = ce[i];
        unsigned u0 = P2[(size_t)(unsigned)e0 * 16 + f2];
        float v0 = __uint_as_float((unsigned)(e0 >> 32));
        ax0 += v0 * bflo(u0); ay0 += v0 * bfhi(u0);
    }
    float ax = ax0 + ax1, ay = ay0 + ay1;
    ax += __shfl_xor(ax, 16); ay += __shfl_xor(ay, 16);
    ax += __shfl_xor(ax, 32); ay += __shfl_xor(ay, 32);
    if (lane < 16) {
        float2 o; o.x = ax; o.y = ay;
        ((float2*)out)[(size_t)node * 16 + f2] = o;
    }
}

// ---------------- launch ----------------

extern "C" void kernel_launch(void* const* d_in, const int* in_sizes, int n_in,
                              void* d_out, int out_size, void* d_ws, size_t ws_size,
                              hipStream_t stream) {
    const float* x    = (const float*)d_in[0];
    const int* esrc   = (const int*)d_in[1];
    const int* edst   = (const int*)d_in[2];
    const float* ev   = (const float*)d_in[3];
    const float* W1   = (const float*)d_in[4];
    const float* W2   = (const float*)d_in[5];
    float* out        = (float*)d_out;

    // workspace layout; pre2b is a SEPARATE region (spmm1g2 reads pre1b while writing pre2b)
    unsigned short* pre1b = (unsigned short*)d_ws;            // 6,400,000 ushort (12.8 MB)
    unsigned* pre2b       = (unsigned*)(pre1b + 6400000);     // 800,000 uint (3.2 MB)
    unsigned long long* csr_ev = (unsigned long long*)((char*)d_ws + 26 * 1024 * 1024); // 800,000 u64
    unsigned long long* tmp    = csr_ev + 800000;             // 196*6144 u64 (9.63 MB)
    int* row_ptr          = (int*)(tmp + (size_t)NBUCK * REG_STRIDE);   // 50,001 (pad 50,048)
    int* gcursor          = row_ptr + 50048;                  // 256
    unsigned short* W1t   = (unsigned short*)(gcursor + 256); // 65,536 ushort

    hipLaunchKernelGGL(w1conv_k,   dim3(256),  dim3(256), 0, stream, W1, W1t, gcursor);
    hipLaunchKernelGGL(bucket1_k,  dim3(391),  dim3(256), 0, stream, esrc, edst, ev, gcursor, tmp);
    hipLaunchKernelGGL(bucket2_k,  dim3(NBUCK),dim3(256), 0, stream, gcursor, tmp, csr_ev, row_ptr);

    hipLaunchKernelGGL(gemm1_mfma, dim3(256),  dim3(1024), 0, stream, x, W1t, pre1b);
    hipLaunchKernelGGL(spmm1g2_k,  dim3(12500),dim3(256), 0, stream, row_ptr, csr_ev,
                       (const unsigned*)pre1b, W2, pre2b);
    hipLaunchKernelGGL(spmm2_k,    dim3(12500),dim3(256), 0, stream, row_ptr, csr_ev,
                       (const unsigned*)pre2b, out);
}

// Round 16
// 134.727 us; speedup vs baseline: 1.1080x; 1.1080x over previous
//
#include <hip/hip_runtime.h>
#include <hip/hip_bf16.h>

#define N_NODES 50000
#define N_EDGES 800000
#define N_FEAT 512
#define HIDDEN 128
#define N_CLASSES 32

#define NBUCK 196        // coarse buckets: src>>8 (256-node regions)
#define REG_STRIDE 6144  // slots per region (mean 4081, sigma 64 -> 30+ sigma headroom)
#define NCHUNK 7         // dst-chunks: dst>>13 -> 0..6 (8192-node / 2MB L2 windows)

typedef __attribute__((ext_vector_type(8))) short bf16x8;
typedef __attribute__((ext_vector_type(4))) float f32x4;

// round-to-nearest-even f32 -> bf16 bits (cold paths)
static __device__ __forceinline__ unsigned short f2bf(float f) {
    unsigned u = __float_as_uint(f);
    u += 0x7FFFu + ((u >> 16) & 1u);
    return (unsigned short)(u >> 16);
}
// unpack uint = (bf16_hi<<16)|bf16_lo
static __device__ __forceinline__ float bflo(unsigned u) { return __uint_as_float(u << 16); }
static __device__ __forceinline__ float bfhi(unsigned u) { return __uint_as_float(u & 0xFFFF0000u); }
// HW packed cvt: one v_cvt_pk_bf16_f32 (RNE)
static __device__ __forceinline__ unsigned pack2(float a, float b) {
    union { __hip_bfloat162 h; unsigned u; } c;
    c.h = __float22bfloat162_rn(make_float2(a, b));
    return c.u;
}

// ---------------- CSR build, phase 1: LDS-bucketed coarse scatter ----------------
// record: src(16) | dst(16)<<16 | val_bits<<32

__global__ __launch_bounds__(256) void bucket1_k(const int* __restrict__ src, const int* __restrict__ dst,
                                                 const float* __restrict__ val,
                                                 int* __restrict__ gcursor,
                                                 unsigned long long* __restrict__ tmp) {
    __shared__ int cnt[256];
    __shared__ int lstart[256];
    __shared__ int lcur[256];
    __shared__ int gbase[256];
    __shared__ unsigned long long buf[2048];   // 16 KB
    const int t = threadIdx.x;
    const int e0 = blockIdx.x * 2048;
    const int ne = min(2048, N_EDGES - e0);

    cnt[t] = 0;
    __syncthreads();

    unsigned long long rec[8];
    int rb[8];
#pragma unroll
    for (int j = 0; j < 8; ++j) {
        int p = j * 256 + t;
        rec[j] = 0; rb[j] = -1;
        if (p < ne) {
            int i = e0 + p;
            unsigned s = (unsigned)src[i];
            rec[j] = (unsigned long long)(s | ((unsigned)dst[i] << 16))
                   | ((unsigned long long)__float_as_uint(val[i]) << 32);
            int b = (int)(s >> 8);
            rb[j] = b;
            atomicAdd(&cnt[b], 1);
        }
    }
    __syncthreads();
    const int cv = cnt[t];
    // inclusive scan (Hillis-Steele)
    for (int off = 1; off < 256; off <<= 1) {
        int xv = (t >= off) ? cnt[t - off] : 0;
        __syncthreads();
        cnt[t] += xv;
        __syncthreads();
    }
    lstart[t] = cnt[t] - cv;
    lcur[t]   = cnt[t] - cv;
    if (t < NBUCK) gbase[t] = atomicAdd(&gcursor[t], cv);
    __syncthreads();
    // place records bucket-grouped into LDS
#pragma unroll
    for (int j = 0; j < 8; ++j) {
        if (rb[j] >= 0) {
            int pos = atomicAdd(&lcur[rb[j]], 1);
            buf[pos] = rec[j];
        }
    }
    __syncthreads();
    // burst write-out: consecutive p within a bucket -> consecutive global slots
#pragma unroll
    for (int j = 0; j < 8; ++j) {
        int p = j * 256 + t;
        if (p < ne) {
            unsigned long long r = buf[p];
            int b = (int)((r & 0xFFFFu) >> 8);
            int tgt = gbase[b] + (p - lstart[b]);
            tmp[(size_t)b * REG_STRIDE + tgt] = r;
        }
    }
}

// ---------------- CSR build, phase 2: per-region sort by (node, dst-chunk) + row_ptr ----------------

__global__ __launch_bounds__(256) void bucket2_k(const int* __restrict__ gcursor,
                                                 const unsigned long long* __restrict__ tmp,
                                                 unsigned long long* __restrict__ csr_ev,
                                                 int* __restrict__ row_ptr) {
    __shared__ int lcnt[256 * NCHUNK];   // [node][chunk]
    __shared__ int lcur[256 * NCHUNK];
    __shared__ int rowsum[256];
    __shared__ int cnts[NBUCK];
    __shared__ int base_s;
    const int b = blockIdx.x;
    const int t = threadIdx.x;
    if (t < NBUCK) cnts[t] = gcursor[t];
    for (int j = t; j < 256 * NCHUNK; j += 256) lcnt[j] = 0;
    __syncthreads();
    const int nb = cnts[b];
    if (t == 0) {
        int s = 0;
        for (int r = 0; r < b; ++r) s += cnts[r];
        base_s = s;
    }
    const unsigned long long* reg = tmp + (size_t)b * REG_STRIDE;
    __syncthreads();
    // pass 1: per-(node,chunk) counts (local node = rec & 255; chunk = dst>>13)
    for (int p = t; p < nb; p += 256) {
        unsigned long long r = reg[p];
        int n = (int)(r & 0xFFu);
        int ch = (int)(((r >> 16) & 0xFFFFu) >> 13);
        atomicAdd(&lcnt[n * NCHUNK + ch], 1);
    }
    __syncthreads();
    // two-level scan: per-thread 7-seq sum, Hillis-Steele over row sums
    int rs = 0;
#pragma unroll
    for (int c = 0; c < NCHUNK; ++c) rs += lcnt[t * NCHUNK + c];
    rowsum[t] = rs;
    __syncthreads();
    for (int off = 1; off < 256; off <<= 1) {
        int xv = (t >= off) ? rowsum[t - off] : 0;
        __syncthreads();
        rowsum[t] += xv;
        __syncthreads();
    }
    const int start = base_s + rowsum[t] - rs;   // exclusive row start
    int o = start;
#pragma unroll
    for (int c = 0; c < NCHUNK; ++c) { lcur[t * NCHUNK + c] = o; o += lcnt[t * NCHUNK + c]; }
    int node = b * 256 + t;
    if (node <= N_NODES) row_ptr[node] = start;
    __syncthreads();
    // pass 2: place in (node, chunk) order (L2-hot window)
    for (int p = t; p < nb; p += 256) {
        unsigned long long r = reg[p];
        int n = (int)(r & 0xFFu);
        int ch = (int)(((r >> 16) & 0xFFFFu) >> 13);
        int pos = atomicAdd(&lcur[n * NCHUNK + ch], 1);
        csr_ev[pos] = ((r >> 16) & 0xFFFFull) | (r & 0xFFFFFFFF00000000ull);
    }
}

// ---------------- W1 transpose + bf16 (+ gcursor zero): W1[512][128] -> W1t[128][512] ----------------

__global__ __launch_bounds__(256) void w1conv_k(const float* __restrict__ W1,
                                                unsigned short* __restrict__ W1t,
                                                int* __restrict__ gcursor) {
    if (blockIdx.x == 0 && threadIdx.x < NBUCK) gcursor[threadIdx.x] = 0;
    int id = blockIdx.x * 256 + threadIdx.x;   // 65536
    int c = id >> 9;          // 0..127
    int k = id & 511;         // 0..511
    W1t[(size_t)c * N_FEAT + k] = f2bf(W1[(size_t)k * HIDDEN + c]);
}

// ---------------- GEMM1: whole W1t in LDS; per-wave streaming, FULL-ROW register prefetch ----------------
// Block: 1024 threads = 16 waves, LDS 128 KB, grid 256 = 1 block/CU (4 waves/SIMD, 512 VGPR/wave budget).
// Wave->group map g = w*256 + blockIdx.x (balanced: every block 12-13 active waves).
// Stage: 128 x 1KB fragment chunks via global_load_lds (8 per wave), ONE barrier.
// K-loop: lane issues ALL 32 float4 loads of its row up front (128 VGPR, ~512 B/wave in
// flight; compiler's vmcnt counting drains in order) -> cvt_pk -> setprio(1) 8 MFMA setprio(0).

__global__ __launch_bounds__(1024, 1) void gemm1_mfma(const float* __restrict__ x,
                                                      const unsigned short* __restrict__ W1t,
                                                      unsigned short* __restrict__ pre1b) {
    __shared__ char lds[131072];   // whole W1t, fragment-chunk order

    const int t = threadIdx.x;
    const int w = t >> 6;            // wave 0..15
    const int l = t & 63;
    const int l15 = l & 15;
    const int lhi = l >> 4;

    // stage: wave w loads chunks w*8 .. w*8+7
#pragma unroll
    for (int j = 0; j < 8; ++j) {
        int c = w * 8 + j;           // wave-uniform chunk id
        int n = c & 7, ks = c >> 3;
        int col = n * 16 + l15;
        int k = ks * 32 + lhi * 8;
        __builtin_amdgcn_global_load_lds(W1t + (size_t)col * N_FEAT + k,
                                         (unsigned short*)(lds + c * 1024), 16, 0, 0);
    }
    __syncthreads();   // the only barrier

    const int g = w * 256 + blockIdx.x;    // strided 16-row-group id (balanced per block)
    if (g >= N_NODES / 16) return;

    const float* xr = x + (size_t)(g * 16 + l15) * N_FEAT + lhi * 8;

    f32x4 acc[8];
#pragma unroll
    for (int n = 0; n < 8; ++n) acc[n] = (f32x4){0.f, 0.f, 0.f, 0.f};

    // full-row prefetch: all 32 x float4 issued up front (static indices)
    float4 row[32];
#pragma unroll
    for (int ks = 0; ks < 16; ++ks) {
        row[2 * ks]     = *(const float4*)(xr + ks * 32);
        row[2 * ks + 1] = *(const float4*)(xr + ks * 32 + 4);
    }
#pragma unroll
    for (int ks = 0; ks < 16; ++ks) {
        union { bf16x8 v; __hip_bfloat162 h[4]; } u;
        u.h[0] = __float22bfloat162_rn(make_float2(row[2 * ks].x, row[2 * ks].y));
        u.h[1] = __float22bfloat162_rn(make_float2(row[2 * ks].z, row[2 * ks].w));
        u.h[2] = __float22bfloat162_rn(make_float2(row[2 * ks + 1].x, row[2 * ks + 1].y));
        u.h[3] = __float22bfloat162_rn(make_float2(row[2 * ks + 1].z, row[2 * ks + 1].w));
        const char* bp = lds + (ks * 8) * 1024 + l * 16;
        __builtin_amdgcn_s_setprio(1);
#pragma unroll
        for (int n = 0; n < 8; ++n) {
            bf16x8 bf = *(const bf16x8*)(bp + n * 1024);
            acc[n] = __builtin_amdgcn_mfma_f32_16x16x32_bf16(u.v, bf, acc[n], 0, 0, 0);
        }
        __builtin_amdgcn_s_setprio(0);
    }
    // epilogue: C/D layout col=lane&15, row=(lane>>4)*4+reg
    unsigned short* orow = pre1b + (size_t)(g * 16 + lhi * 4) * HIDDEN + l15;
#pragma unroll
    for (int n = 0; n < 8; ++n)
#pragma unroll
        for (int j = 0; j < 4; ++j)
            orow[(size_t)j * HIDDEN + n * 16] = f2bf(acc[n][j]);
}

// ---------------- SpMM1: hb = bf16(relu(A @ pre1)), one wave per node, 4-edge unroll ----------------

__global__ __launch_bounds__(256) void spmm1_k(const int* __restrict__ rp,
                                               const unsigned long long* __restrict__ ce,
                                               const unsigned* __restrict__ P,
                                               unsigned* __restrict__ hb) {
    const int g = threadIdx.x >> 6;
    const int lane = threadIdx.x & 63;
    const int node = blockIdx.x * 4 + g;
    if (node >= N_NODES) return;
    const int s = rp[node], e = rp[node + 1];
    float2 a0, a1, a2, a3;
    a0.x = a0.y = a1.x = a1.y = 0.f;
    a2.x = a2.y = a3.x = a3.y = 0.f;
    int i = s;
    for (; i + 4 <= e; i += 4) {
        unsigned long long e0 = ce[i],     e1 = ce[i + 1];
        unsigned long long e2 = ce[i + 2], e3 = ce[i + 3];
        unsigned u0 = P[(size_t)(unsigned)e0 * 64 + lane];
        unsigned u1 = P[(size_t)(unsigned)e1 * 64 + lane];
        unsigned u2 = P[(size_t)(unsigned)e2 * 64 + lane];
        unsigned u3 = P[(size_t)(unsigned)e3 * 64 + lane];
        float v0 = __uint_as_float((unsigned)(e0 >> 32));
        float v1 = __uint_as_float((unsigned)(e1 >> 32));
        float v2 = __uint_as_float((unsigned)(e2 >> 32));
        float v3 = __uint_as_float((unsigned)(e3 >> 32));
        a0.x += v0 * bflo(u0); a0.y += v0 * bfhi(u0);
        a1.x += v1 * bflo(u1); a1.y += v1 * bfhi(u1);
        a2.x += v2 * bflo(u2); a2.y += v2 * bfhi(u2);
        a3.x += v3 * bflo(u3); a3.y += v3 * bfhi(u3);
    }
    for (; i < e; ++i) {
        unsigned long long e0 = ce[i];
        unsigned u0 = P[(size_t)(unsigned)e0 * 64 + lane];
        float v0 = __uint_as_float((unsigned)(e0 >> 32));
        a0.x += v0 * bflo(u0); a0.y += v0 * bfhi(u0);
    }
    a0.x += a1.x + a2.x + a3.x;
    a0.y += a1.y + a2.y + a3.y;
    a0.x = a0.x > 0.f ? a0.x : 0.f;
    a0.y = a0.y > 0.f ? a0.y : 0.f;
    hb[(size_t)node * 64 + lane] = pack2(a0.x, a0.y);
}

// ---------------- GEMM2: pre2b[50000,32] = bf16(h @ W2) ----------------

__global__ __launch_bounds__(256) void gemm2_k(const unsigned* __restrict__ hb,
                                               const float* __restrict__ W2,
                                               unsigned short* __restrict__ pre2b) {
    __shared__ float hs[32][132];
    __shared__ float w2s[HIDDEN][N_CLASSES];
    const int t = threadIdx.x;
    const int row0 = blockIdx.x * 32;
#pragma unroll
    for (int j = 0; j < 4; ++j) {        // W2: 1024 float4
        int f = j * 256 + t;
        int r = f >> 3;
        int c = (f & 7) << 2;
        *(float4*)&w2s[r][c] = *(const float4*)(W2 + (size_t)r * N_CLASSES + c);
    }
#pragma unroll
    for (int j = 0; j < 2; ++j) {        // h tile: 32 rows x 64 uints = 2048 uints
        int f = j * 256 + t;
        int r = f >> 4;                  // 0..31
        int cu = (f & 15) << 2;          // uint col 0..60 step 4
        int grr = row0 + r;
        if (grr >= N_NODES) grr = N_NODES - 1;
        uint4 u = *(const uint4*)(hb + (size_t)grr * 64 + cu);
        hs[r][2 * cu + 0] = bflo(u.x); hs[r][2 * cu + 1] = bfhi(u.x);
        hs[r][2 * cu + 2] = bflo(u.y); hs[r][2 * cu + 3] = bfhi(u.y);
        hs[r][2 * cu + 4] = bflo(u.z); hs[r][2 * cu + 5] = bfhi(u.z);
        hs[r][2 * cu + 6] = bflo(u.w); hs[r][2 * cu + 7] = bfhi(u.w);
    }
    __syncthreads();
    const int r = t >> 3;
    const int c = (t & 7) << 2;
    float4 acc; acc.x = acc.y = acc.z = acc.w = 0.f;
#pragma unroll 16
    for (int kk = 0; kk < HIDDEN; ++kk) {
        float a = hs[r][kk];
        float4 b = *(const float4*)&w2s[kk][c];
        acc.x += a * b.x; acc.y += a * b.y; acc.z += a * b.z; acc.w += a * b.w;
    }
    int grr = row0 + r;
    if (grr < N_NODES) {
        uint2 o;
        o.x = pack2(acc.x, acc.y);
        o.y = pack2(acc.z, acc.w);
        *(uint2*)&pre2b[(size_t)grr * N_CLASSES + c] = o;
    }
}

// ---------------- SpMM2: out = A @ pre2 ; 16 lanes/edge, 2-deep unroll (8 edges in flight) ----------------

__global__ __launch_bounds__(256) void spmm2_k(const int* __restrict__ rp,
                                               const unsigned long long* __restrict__ ce,
                                               const unsigned* __restrict__ P2,
                                               float* __restrict__ out) {
    const int g = threadIdx.x >> 6;
    const int lane = threadIdx.x & 63;
    const int node = blockIdx.x * 4 + g;
    if (node >= N_NODES) return;
    const int s = rp[node], e = rp[node + 1];
    const int f2 = lane & 15;      // uint index: feats 2*f2, 2*f2+1
    const int par = lane >> 4;     // 0..3
    float ax0 = 0.f, ay0 = 0.f, ax1 = 0.f, ay1 = 0.f;
    int i = s + par;
    for (; i + 4 < e; i += 8) {
        unsigned long long e0 = ce[i], e1 = ce[i + 4];
        unsigned u0 = P2[(size_t)(unsigned)e0 * 16 + f2];
        unsigned u1 = P2[(size_t)(unsigned)e1 * 16 + f2];
        float v0 = __uint_as_float((unsigned)(e0 >> 32));
        float v1 = __uint_as_float((unsigned)(e1 >> 32));
        ax0 += v0 * bflo(u0); ay0 += v0 * bfhi(u0);
        ax1 += v1 * bflo(u1); ay1 += v1 * bfhi(u1);
    }
    if (i < e) {
        unsigned long long e0 = ce[i];
        unsigned u0 = P2[(size_t)(unsigned)e0 * 16 + f2];
        float v0 = __uint_as_float((unsigned)(e0 >> 32));
        ax0 += v0 * bflo(u0); ay0 += v0 * bfhi(u0);
    }
    float ax = ax0 + ax1, ay = ay0 + ay1;
    ax += __shfl_xor(ax, 16); ay += __shfl_xor(ay, 16);
    ax += __shfl_xor(ax, 32); ay += __shfl_xor(ay, 32);
    if (lane < 16) {
        float2 o; o.x = ax; o.y = ay;
        ((float2*)out)[(size_t)node * 16 + f2] = o;
    }
}

// ---------------- launch ----------------

extern "C" void kernel_launch(void* const* d_in, const int* in_sizes, int n_in,
                              void* d_out, int out_size, void* d_ws, size_t ws_size,
                              hipStream_t stream) {
    const float* x    = (const float*)d_in[0];
    const int* esrc   = (const int*)d_in[1];
    const int* edst   = (const int*)d_in[2];
    const float* ev   = (const float*)d_in[3];
    const float* W1   = (const float*)d_in[4];
    const float* W2   = (const float*)d_in[5];
    float* out        = (float*)d_out;

    // workspace layout; pre2b aliases pre1b (pre1b dead after spmm1)
    unsigned short* pre1b = (unsigned short*)d_ws;            // 6,400,000 ushort (12.8 MB)
    unsigned* hb          = (unsigned*)(pre1b + 6400000);     // 3,200,000 uint (12.8 MB)
    unsigned short* pre2b = pre1b;                            // alias
    unsigned long long* csr_ev = (unsigned long long*)(hb + 3200000);   // 800,000 u64 (6.4 MB)
    unsigned long long* tmp    = csr_ev + 800000;             // 196*6144 u64 (9.63 MB)
    int* row_ptr          = (int*)(tmp + (size_t)NBUCK * REG_STRIDE);   // 50,001 (pad 50,048)
    int* gcursor          = row_ptr + 50048;                  // 256
    unsigned short* W1t   = (unsigned short*)(gcursor + 256); // 65,536 ushort

    hipLaunchKernelGGL(w1conv_k,   dim3(256),  dim3(256), 0, stream, W1, W1t, gcursor);
    hipLaunchKernelGGL(bucket1_k,  dim3(391),  dim3(256), 0, stream, esrc, edst, ev, gcursor, tmp);
    hipLaunchKernelGGL(bucket2_k,  dim3(NBUCK),dim3(256), 0, stream, gcursor, tmp, csr_ev, row_ptr);

    hipLaunchKernelGGL(gemm1_mfma, dim3(256),  dim3(1024), 0, stream, x, W1t, pre1b);
    hipLaunchKernelGGL(spmm1_k,    dim3(12500),dim3(256), 0, stream, row_ptr, csr_ev, (const unsigned*)pre1b, hb);
    hipLaunchKernelGGL(gemm2_k,    dim3(1563), dim3(256), 0, stream, hb, W2, pre2b);
    hipLaunchKernelGGL(spmm2_k,    dim3(12500),dim3(256), 0, stream, row_ptr, csr_ev, (const unsigned*)pre2b, out);
}

// Round 17
// 126.374 us; speedup vs baseline: 1.1813x; 1.0661x over previous
//
#include <hip/hip_runtime.h>
#include <hip/hip_bf16.h>

#define N_NODES 50000
#define N_EDGES 800000
#define N_FEAT 512
#define HIDDEN 128
#define N_CLASSES 32

#define NBUCK 196        // coarse buckets: src>>8 (256-node regions)
#define REG_STRIDE 6144  // slots per region (mean 4081, sigma 64 -> 30+ sigma headroom)
#define NCHUNK 7         // dst-chunks: dst>>13 -> 0..6 (8192-node / 2MB L2 windows)

typedef __attribute__((ext_vector_type(8))) short bf16x8;
typedef __attribute__((ext_vector_type(4))) float f32x4;

// round-to-nearest-even f32 -> bf16 bits (cold paths)
static __device__ __forceinline__ unsigned short f2bf(float f) {
    unsigned u = __float_as_uint(f);
    u += 0x7FFFu + ((u >> 16) & 1u);
    return (unsigned short)(u >> 16);
}
// unpack uint = (bf16_hi<<16)|bf16_lo
static __device__ __forceinline__ float bflo(unsigned u) { return __uint_as_float(u << 16); }
static __device__ __forceinline__ float bfhi(unsigned u) { return __uint_as_float(u & 0xFFFF0000u); }
// HW packed cvt: one v_cvt_pk_bf16_f32 (RNE)
static __device__ __forceinline__ unsigned pack2(float a, float b) {
    union { __hip_bfloat162 h; unsigned u; } c;
    c.h = __float22bfloat162_rn(make_float2(a, b));
    return c.u;
}

// ---------------- CSR build, phase 1: LDS-bucketed coarse scatter ----------------
// record: src(16) | dst(16)<<16 | val_bits<<32

__global__ __launch_bounds__(256) void bucket1_k(const int* __restrict__ src, const int* __restrict__ dst,
                                                 const float* __restrict__ val,
                                                 int* __restrict__ gcursor,
                                                 unsigned long long* __restrict__ tmp) {
    __shared__ int cnt[256];
    __shared__ int lstart[256];
    __shared__ int lcur[256];
    __shared__ int gbase[256];
    __shared__ unsigned long long buf[2048];   // 16 KB
    const int t = threadIdx.x;
    const int e0 = blockIdx.x * 2048;
    const int ne = min(2048, N_EDGES - e0);

    cnt[t] = 0;
    __syncthreads();

    unsigned long long rec[8];
    int rb[8];
#pragma unroll
    for (int j = 0; j < 8; ++j) {
        int p = j * 256 + t;
        rec[j] = 0; rb[j] = -1;
        if (p < ne) {
            int i = e0 + p;
            unsigned s = (unsigned)src[i];
            rec[j] = (unsigned long long)(s | ((unsigned)dst[i] << 16))
                   | ((unsigned long long)__float_as_uint(val[i]) << 32);
            int b = (int)(s >> 8);
            rb[j] = b;
            atomicAdd(&cnt[b], 1);
        }
    }
    __syncthreads();
    const int cv = cnt[t];
    // inclusive scan (Hillis-Steele)
    for (int off = 1; off < 256; off <<= 1) {
        int xv = (t >= off) ? cnt[t - off] : 0;
        __syncthreads();
        cnt[t] += xv;
        __syncthreads();
    }
    lstart[t] = cnt[t] - cv;
    lcur[t]   = cnt[t] - cv;
    if (t < NBUCK) gbase[t] = atomicAdd(&gcursor[t], cv);
    __syncthreads();
    // place records bucket-grouped into LDS
#pragma unroll
    for (int j = 0; j < 8; ++j) {
        if (rb[j] >= 0) {
            int pos = atomicAdd(&lcur[rb[j]], 1);
            buf[pos] = rec[j];
        }
    }
    __syncthreads();
    // burst write-out: consecutive p within a bucket -> consecutive global slots
#pragma unroll
    for (int j = 0; j < 8; ++j) {
        int p = j * 256 + t;
        if (p < ne) {
            unsigned long long r = buf[p];
            int b = (int)((r & 0xFFFFu) >> 8);
            int tgt = gbase[b] + (p - lstart[b]);
            tmp[(size_t)b * REG_STRIDE + tgt] = r;
        }
    }
}

// ---------------- CSR build, phase 2: per-region sort by (node, dst-chunk) + row_ptr ----------------

__global__ __launch_bounds__(256) void bucket2_k(const int* __restrict__ gcursor,
                                                 const unsigned long long* __restrict__ tmp,
                                                 unsigned long long* __restrict__ csr_ev,
                                                 int* __restrict__ row_ptr) {
    __shared__ int lcnt[256 * NCHUNK];   // [node][chunk]
    __shared__ int lcur[256 * NCHUNK];
    __shared__ int rowsum[256];
    __shared__ int cnts[NBUCK];
    __shared__ int base_s;
    const int b = blockIdx.x;
    const int t = threadIdx.x;
    if (t < NBUCK) cnts[t] = gcursor[t];
    for (int j = t; j < 256 * NCHUNK; j += 256) lcnt[j] = 0;
    __syncthreads();
    const int nb = cnts[b];
    if (t == 0) {
        int s = 0;
        for (int r = 0; r < b; ++r) s += cnts[r];
        base_s = s;
    }
    const unsigned long long* reg = tmp + (size_t)b * REG_STRIDE;
    __syncthreads();
    // pass 1: per-(node,chunk) counts (local node = rec & 255; chunk = dst>>13)
    for (int p = t; p < nb; p += 256) {
        unsigned long long r = reg[p];
        int n = (int)(r & 0xFFu);
        int ch = (int)(((r >> 16) & 0xFFFFu) >> 13);
        atomicAdd(&lcnt[n * NCHUNK + ch], 1);
    }
    __syncthreads();
    // two-level scan: per-thread 7-seq sum, Hillis-Steele over row sums
    int rs = 0;
#pragma unroll
    for (int c = 0; c < NCHUNK; ++c) rs += lcnt[t * NCHUNK + c];
    rowsum[t] = rs;
    __syncthreads();
    for (int off = 1; off < 256; off <<= 1) {
        int xv = (t >= off) ? rowsum[t - off] : 0;
        __syncthreads();
        rowsum[t] += xv;
        __syncthreads();
    }
    const int start = base_s + rowsum[t] - rs;   // exclusive row start
    int o = start;
#pragma unroll
    for (int c = 0; c < NCHUNK; ++c) { lcur[t * NCHUNK + c] = o; o += lcnt[t * NCHUNK + c]; }
    int node = b * 256 + t;
    if (node <= N_NODES) row_ptr[node] = start;
    __syncthreads();
    // pass 2: place in (node, chunk) order (L2-hot window)
    for (int p = t; p < nb; p += 256) {
        unsigned long long r = reg[p];
        int n = (int)(r & 0xFFu);
        int ch = (int)(((r >> 16) & 0xFFFFu) >> 13);
        int pos = atomicAdd(&lcur[n * NCHUNK + ch], 1);
        csr_ev[pos] = ((r >> 16) & 0xFFFFull) | (r & 0xFFFFFFFF00000000ull);
    }
}

// ---------------- W1 transpose + bf16 (+ gcursor zero): W1[512][128] -> W1t[128][512] ----------------

__global__ __launch_bounds__(256) void w1conv_k(const float* __restrict__ W1,
                                                unsigned short* __restrict__ W1t,
                                                int* __restrict__ gcursor) {
    if (blockIdx.x == 0 && threadIdx.x < NBUCK) gcursor[threadIdx.x] = 0;
    int id = blockIdx.x * 256 + threadIdx.x;   // 65536
    int c = id >> 9;          // 0..127
    int k = id & 511;         // 0..511
    W1t[(size_t)c * N_FEAT + k] = f2bf(W1[(size_t)k * HIDDEN + c]);
}

// ---------------- GEMM1: whole W1t in LDS; balanced per-wave streaming, depth-3 prefetch ----------------
// Block: 1024 threads = 16 waves, LDS 128 KB, grid 256 = exactly 1 block/CU (4 waves/SIMD).
// Wave->group map g = w*256 + blockIdx.x (balanced: every block 12-13 active waves).
// Stage: 128 x 1KB fragment chunks via global_load_lds (8 per wave), ONE barrier.
// K-loop (fully unrolled, static rolling indices): depth-3 reg prefetch -> cvt_pk ->
// setprio(1) 8x{ds_read_b128 + MFMA} setprio(0).

__global__ __launch_bounds__(1024, 1) void gemm1_mfma(const float* __restrict__ x,
                                                      const unsigned short* __restrict__ W1t,
                                                      unsigned short* __restrict__ pre1b) {
    __shared__ char lds[131072];   // whole W1t, fragment-chunk order

    const int t = threadIdx.x;
    const int w = t >> 6;            // wave 0..15
    const int l = t & 63;
    const int l15 = l & 15;
    const int lhi = l >> 4;

    // stage: wave w loads chunks w*8 .. w*8+7
#pragma unroll
    for (int j = 0; j < 8; ++j) {
        int c = w * 8 + j;           // wave-uniform chunk id
        int n = c & 7, ks = c >> 3;
        int col = n * 16 + l15;
        int k = ks * 32 + lhi * 8;
        __builtin_amdgcn_global_load_lds(W1t + (size_t)col * N_FEAT + k,
                                         (unsigned short*)(lds + c * 1024), 16, 0, 0);
    }
    __syncthreads();   // the only barrier

    const int g = w * 256 + blockIdx.x;    // strided 16-row-group id (balanced per block)
    if (g >= N_NODES / 16) return;

    const float* xr = x + (size_t)(g * 16 + l15) * N_FEAT + lhi * 8;

    f32x4 acc[8];
#pragma unroll
    for (int n = 0; n < 8; ++n) acc[n] = (f32x4){0.f, 0.f, 0.f, 0.f};

    // depth-3 rolling prefetch pipeline (static indices after full unroll)
    float4 qa[3], qb[3];
#pragma unroll
    for (int j = 0; j < 3; ++j) {
        qa[j] = *(const float4*)(xr + j * 32);
        qb[j] = *(const float4*)(xr + j * 32 + 4);
    }
#pragma unroll
    for (int ks = 0; ks < 16; ++ks) {
        float4 c0 = qa[ks % 3], c1 = qb[ks % 3];
        if (ks + 3 < 16) {
            qa[ks % 3] = *(const float4*)(xr + (ks + 3) * 32);
            qb[ks % 3] = *(const float4*)(xr + (ks + 3) * 32 + 4);
        }
        union { bf16x8 v; __hip_bfloat162 h[4]; } u;
        u.h[0] = __float22bfloat162_rn(make_float2(c0.x, c0.y));
        u.h[1] = __float22bfloat162_rn(make_float2(c0.z, c0.w));
        u.h[2] = __float22bfloat162_rn(make_float2(c1.x, c1.y));
        u.h[3] = __float22bfloat162_rn(make_float2(c1.z, c1.w));
        const char* bp = lds + (ks * 8) * 1024 + l * 16;
        __builtin_amdgcn_s_setprio(1);
#pragma unroll
        for (int n = 0; n < 8; ++n) {
            bf16x8 bf = *(const bf16x8*)(bp + n * 1024);
            acc[n] = __builtin_amdgcn_mfma_f32_16x16x32_bf16(u.v, bf, acc[n], 0, 0, 0);
        }
        __builtin_amdgcn_s_setprio(0);
    }
    // epilogue: C/D layout col=lane&15, row=(lane>>4)*4+reg
    unsigned short* orow = pre1b + (size_t)(g * 16 + lhi * 4) * HIDDEN + l15;
#pragma unroll
    for (int n = 0; n < 8; ++n)
#pragma unroll
        for (int j = 0; j < 4; ++j)
            orow[(size_t)j * HIDDEN + n * 16] = f2bf(acc[n][j]);
}

// ---------------- SpMM1: hb = bf16(relu(A @ pre1)), one wave per node, 8-gather-deep edge loop ----------------

__global__ __launch_bounds__(256) void spmm1_k(const int* __restrict__ rp,
                                               const unsigned long long* __restrict__ ce,
                                               const unsigned* __restrict__ P,
                                               unsigned* __restrict__ hb) {
    const int g = threadIdx.x >> 6;
    const int lane = threadIdx.x & 63;
    const int node = blockIdx.x * 4 + g;
    if (node >= N_NODES) return;
    const int s = rp[node], e = rp[node + 1];
    float2 a0, a1, a2, a3;
    a0.x = a0.y = a1.x = a1.y = 0.f;
    a2.x = a2.y = a3.x = a3.y = 0.f;
    int i = s;
    // 8-deep: all 8 edge-loads + 8 gathers issued before the FMA block
    for (; i + 8 <= e; i += 8) {
        unsigned long long e0 = ce[i],     e1 = ce[i + 1];
        unsigned long long e2 = ce[i + 2], e3 = ce[i + 3];
        unsigned long long e4 = ce[i + 4], e5 = ce[i + 5];
        unsigned long long e6 = ce[i + 6], e7 = ce[i + 7];
        unsigned u0 = P[(size_t)(unsigned)e0 * 64 + lane];
        unsigned u1 = P[(size_t)(unsigned)e1 * 64 + lane];
        unsigned u2 = P[(size_t)(unsigned)e2 * 64 + lane];
        unsigned u3 = P[(size_t)(unsigned)e3 * 64 + lane];
        unsigned u4 = P[(size_t)(unsigned)e4 * 64 + lane];
        unsigned u5 = P[(size_t)(unsigned)e5 * 64 + lane];
        unsigned u6 = P[(size_t)(unsigned)e6 * 64 + lane];
        unsigned u7 = P[(size_t)(unsigned)e7 * 64 + lane];
        float v0 = __uint_as_float((unsigned)(e0 >> 32));
        float v1 = __uint_as_float((unsigned)(e1 >> 32));
        float v2 = __uint_as_float((unsigned)(e2 >> 32));
        float v3 = __uint_as_float((unsigned)(e3 >> 32));
        float v4 = __uint_as_float((unsigned)(e4 >> 32));
        float v5 = __uint_as_float((unsigned)(e5 >> 32));
        float v6 = __uint_as_float((unsigned)(e6 >> 32));
        float v7 = __uint_as_float((unsigned)(e7 >> 32));
        a0.x += v0 * bflo(u0); a0.y += v0 * bfhi(u0);
        a1.x += v1 * bflo(u1); a1.y += v1 * bfhi(u1);
        a2.x += v2 * bflo(u2); a2.y += v2 * bfhi(u2);
        a3.x += v3 * bflo(u3); a3.y += v3 * bfhi(u3);
        a0.x += v4 * bflo(u4); a0.y += v4 * bfhi(u4);
        a1.x += v5 * bflo(u5); a1.y += v5 * bfhi(u5);
        a2.x += v6 * bflo(u6); a2.y += v6 * bfhi(u6);
        a3.x += v7 * bflo(u7); a3.y += v7 * bfhi(u7);
    }
    if (i + 4 <= e) {
        unsigned long long e0 = ce[i],     e1 = ce[i + 1];
        unsigned long long e2 = ce[i + 2], e3 = ce[i + 3];
        unsigned u0 = P[(size_t)(unsigned)e0 * 64 + lane];
        unsigned u1 = P[(size_t)(unsigned)e1 * 64 + lane];
        unsigned u2 = P[(size_t)(unsigned)e2 * 64 + lane];
        unsigned u3 = P[(size_t)(unsigned)e3 * 64 + lane];
        float v0 = __uint_as_float((unsigned)(e0 >> 32));
        float v1 = __uint_as_float((unsigned)(e1 >> 32));
        float v2 = __uint_as_float((unsigned)(e2 >> 32));
        float v3 = __uint_as_float((unsigned)(e3 >> 32));
        a0.x += v0 * bflo(u0); a0.y += v0 * bfhi(u0);
        a1.x += v1 * bflo(u1); a1.y += v1 * bfhi(u1);
        a2.x += v2 * bflo(u2); a2.y += v2 * bfhi(u2);
        a3.x += v3 * bflo(u3); a3.y += v3 * bfhi(u3);
        i += 4;
    }
    if (i + 2 <= e) {
        unsigned long long e0 = ce[i], e1 = ce[i + 1];
        unsigned u0 = P[(size_t)(unsigned)e0 * 64 + lane];
        unsigned u1 = P[(size_t)(unsigned)e1 * 64 + lane];
        float v0 = __uint_as_float((unsigned)(e0 >> 32));
        float v1 = __uint_as_float((unsigned)(e1 >> 32));
        a0.x += v0 * bflo(u0); a0.y += v0 * bfhi(u0);
        a1.x += v1 * bflo(u1); a1.y += v1 * bfhi(u1);
        i += 2;
    }
    if (i < e) {
        unsigned long long e0 = ce[i];
        unsigned u0 = P[(size_t)(unsigned)e0 * 64 + lane];
        float v0 = __uint_as_float((unsigned)(e0 >> 32));
        a0.x += v0 * bflo(u0); a0.y += v0 * bfhi(u0);
    }
    a0.x += a1.x + a2.x + a3.x;
    a0.y += a1.y + a2.y + a3.y;
    a0.x = a0.x > 0.f ? a0.x : 0.f;
    a0.y = a0.y > 0.f ? a0.y : 0.f;
    hb[(size_t)node * 64 + lane] = pack2(a0.x, a0.y);
}

// ---------------- GEMM2: pre2b[50000,32] = bf16(h @ W2) ----------------

__global__ __launch_bounds__(256) void gemm2_k(const unsigned* __restrict__ hb,
                                               const float* __restrict__ W2,
                                               unsigned short* __restrict__ pre2b) {
    __shared__ float hs[32][132];
    __shared__ float w2s[HIDDEN][N_CLASSES];
    const int t = threadIdx.x;
    const int row0 = blockIdx.x * 32;
#pragma unroll
    for (int j = 0; j < 4; ++j) {        // W2: 1024 float4
        int f = j * 256 + t;
        int r = f >> 3;
        int c = (f & 7) << 2;
        *(float4*)&w2s[r][c] = *(const float4*)(W2 + (size_t)r * N_CLASSES + c);
    }
#pragma unroll
    for (int j = 0; j < 2; ++j) {        // h tile: 32 rows x 64 uints = 2048 uints
        int f = j * 256 + t;
        int r = f >> 4;                  // 0..31
        int cu = (f & 15) << 2;          // uint col 0..60 step 4
        int grr = row0 + r;
        if (grr >= N_NODES) grr = N_NODES - 1;
        uint4 u = *(const uint4*)(hb + (size_t)grr * 64 + cu);
        hs[r][2 * cu + 0] = bflo(u.x); hs[r][2 * cu + 1] = bfhi(u.x);
        hs[r][2 * cu + 2] = bflo(u.y); hs[r][2 * cu + 3] = bfhi(u.y);
        hs[r][2 * cu + 4] = bflo(u.z); hs[r][2 * cu + 5] = bfhi(u.z);
        hs[r][2 * cu + 6] = bflo(u.w); hs[r][2 * cu + 7] = bfhi(u.w);
    }
    __syncthreads();
    const int r = t >> 3;
    const int c = (t & 7) << 2;
    float4 acc; acc.x = acc.y = acc.z = acc.w = 0.f;
#pragma unroll 16
    for (int kk = 0; kk < HIDDEN; ++kk) {
        float a = hs[r][kk];
        float4 b = *(const float4*)&w2s[kk][c];
        acc.x += a * b.x; acc.y += a * b.y; acc.z += a * b.z; acc.w += a * b.w;
    }
    int grr = row0 + r;
    if (grr < N_NODES) {
        uint2 o;
        o.x = pack2(acc.x, acc.y);
        o.y = pack2(acc.z, acc.w);
        *(uint2*)&pre2b[(size_t)grr * N_CLASSES + c] = o;
    }
}

// ---------------- SpMM2: out = A @ pre2 ; 16 lanes/edge, 2-deep unroll (8 edges in flight) ----------------

__global__ __launch_bounds__(256) void spmm2_k(const int* __restrict__ rp,
                                               const unsigned long long* __restrict__ ce,
                                               const unsigned* __restrict__ P2,
                                               float* __restrict__ out) {
    const int g = threadIdx.x >> 6;
    const int lane = threadIdx.x & 63;
    const int node = blockIdx.x * 4 + g;
    if (node >= N_NODES) return;
    const int s = rp[node], e = rp[node + 1];
    const int f2 = lane & 15;      // uint index: feats 2*f2, 2*f2+1
    const int par = lane >> 4;     // 0..3
    float ax0 = 0.f, ay0 = 0.f, ax1 = 0.f, ay1 = 0.f;
    int i = s + par;
    for (; i + 4 < e; i += 8) {
        unsigned long long e0 = ce[i], e1 = ce[i + 4];
        unsigned u0 = P2[(size_t)(unsigned)e0 * 16 + f2];
        unsigned u1 = P2[(size_t)(unsigned)e1 * 16 + f2];
        float v0 = __uint_as_float((unsigned)(e0 >> 32));
        float v1 = __uint_as_float((unsigned)(e1 >> 32));
        ax0 += v0 * bflo(u0); ay0 += v0 * bfhi(u0);
        ax1 += v1 * bflo(u1); ay1 += v1 * bfhi(u1);
    }
    if (i < e) {
        unsigned long long e0 = ce[i];
        unsigned u0 = P2[(size_t)(unsigned)e0 * 16 + f2];
        float v0 = __uint_as_float((unsigned)(e0 >> 32));
        ax0 += v0 * bflo(u0); ay0 += v0 * bfhi(u0);
    }
    float ax = ax0 + ax1, ay = ay0 + ay1;
    ax += __shfl_xor(ax, 16); ay += __shfl_xor(ay, 16);
    ax += __shfl_xor(ax, 32); ay += __shfl_xor(ay, 32);
    if (lane < 16) {
        float2 o; o.x = ax; o.y = ay;
        ((float2*)out)[(size_t)node * 16 + f2] = o;
    }
}

// ---------------- launch ----------------

extern "C" void kernel_launch(void* const* d_in, const int* in_sizes, int n_in,
                              void* d_out, int out_size, void* d_ws, size_t ws_size,
                              hipStream_t stream) {
    const float* x    = (const float*)d_in[0];
    const int* esrc   = (const int*)d_in[1];
    const int* edst   = (const int*)d_in[2];
    const float* ev   = (const float*)d_in[3];
    const float* W1   = (const float*)d_in[4];
    const float* W2   = (const float*)d_in[5];
    float* out        = (float*)d_out;

    // workspace layout; pre2b aliases pre1b (pre1b dead after spmm1)
    unsigned short* pre1b = (unsigned short*)d_ws;            // 6,400,000 ushort (12.8 MB)
    unsigned* hb          = (unsigned*)(pre1b + 6400000);     // 3,200,000 uint (12.8 MB)
    unsigned short* pre2b = pre1b;                            // alias
    unsigned long long* csr_ev = (unsigned long long*)(hb + 3200000);   // 800,000 u64 (6.4 MB)
    unsigned long long* tmp    = csr_ev + 800000;             // 196*6144 u64 (9.63 MB)
    int* row_ptr          = (int*)(tmp + (size_t)NBUCK * REG_STRIDE);   // 50,001 (pad 50,048)
    int* gcursor          = row_ptr + 50048;                  // 256
    unsigned short* W1t   = (unsigned short*)(gcursor + 256); // 65,536 ushort

    hipLaunchKernelGGL(w1conv_k,   dim3(256),  dim3(256), 0, stream, W1, W1t, gcursor);
    hipLaunchKernelGGL(bucket1_k,  dim3(391),  dim3(256), 0, stream, esrc, edst, ev, gcursor, tmp);
    hipLaunchKernelGGL(bucket2_k,  dim3(NBUCK),dim3(256), 0, stream, gcursor, tmp, csr_ev, row_ptr);

    hipLaunchKernelGGL(gemm1_mfma, dim3(256),  dim3(1024), 0, stream, x, W1t, pre1b);
    hipLaunchKernelGGL(spmm1_k,    dim3(12500),dim3(256), 0, stream, row_ptr, csr_ev, (const unsigned*)pre1b, hb);
    hipLaunchKernelGGL(gemm2_k,    dim3(1563), dim3(256), 0, stream, hb, W2, pre2b);
    hipLaunchKernelGGL(spmm2_k,    dim3(12500),dim3(256), 0, stream, row_ptr, csr_ev, (const unsigned*)pre2b, out);
}